// Round 3
// baseline (361.583 us; speedup 1.0000x reference)
//
#include <hip/hip_runtime.h>

#define SEQ 5000
#define BATCH 64
#define DIM 128

#define TPB1 1024            // rank kernel: 16 waves to hide random-LDS latency
#define TPB2 512             // emit kernel
#define ROWS_PER_ITER (TPB2 / 32)  // 16 rows per block-iteration
#define EMIT_BLOCKS 2000     // 2000*16*10 = 320000 rows: exact cover, no tail

typedef float f32x4 __attribute__((ext_vector_type(4)));

// ---------------------------------------------------------------------------
// Kernel 1: one block per batch. Wyllie pointer-doubling list ranking of the
// successor cycle in LDS: word = (dist<<16)|next, cycle broken at node 0
// (dist=0,next=0). After 13 doublings (2^13=8192>5000), dist[i] = #steps i->0,
// visited_time = SEQ - dist. Writes vt (as f32) straight to its final output
// location; the emit kernel reconstructs idx = (vt==SEQ) ? 0 : vt.
// Estimated ~10-15 us (LDS-pipe bound, 64 CUs).
// ---------------------------------------------------------------------------
__global__ __launch_bounds__(TPB1) void rank_kernel(
    const int* __restrict__ sol,   // [B][S] int32
    float* __restrict__ vt_out) {  // [B][S] f32 (final output region)
    __shared__ unsigned buf[2][SEQ];  // 40 KB
    const int b = blockIdx.x;
    const int* sp = sol + b * SEQ;

    for (int i = threadIdx.x; i < SEQ; i += TPB1) {
        unsigned nx = (unsigned)sp[i];
        if (nx >= SEQ) nx = 0;  // safety: never triggers on valid input
        buf[0][i] = (i == 0) ? 0u : ((1u << 16) | nx);
    }
    __syncthreads();
    int cur = 0;
#pragma unroll 1
    for (int it = 0; it < 13; ++it) {
        for (int i = threadIdx.x; i < SEQ; i += TPB1) {
            unsigned w  = buf[cur][i];
            unsigned w2 = buf[cur][w & 0xFFFFu];
            buf[cur ^ 1][i] = (w & 0xFFFF0000u) + w2;  // low 16 can't carry
        }
        __syncthreads();
        cur ^= 1;
    }
    for (int i = threadIdx.x; i < SEQ; i += TPB1) {
        int vt = SEQ - (int)(buf[cur][i] >> 16);  // 1..5000; node 0 -> 5000
        vt_out[(size_t)b * SEQ + i] = (float)vt;
    }
}

// ---------------------------------------------------------------------------
// Kernel 2: pure streaming emit. 32 lanes per row; lane c owns channels
// 4c..4c+3. NFE = x@W^T computed in registers (W staged as 2 f32x4/lane),
// PFE = bit-exact 16B gather of pattern[idx] (2.56 MB, L2-resident).
// PLAIN stores this round: nontemporal was the prime suspect for emit
// running at ~2.8 TB/s effective vs the 6.2 TB/s the fill kernel proves
// on this buffer. Each half-wave writes contiguous 512 B bursts.
// ---------------------------------------------------------------------------
__global__ __launch_bounds__(TPB2) void emit_kernel(
    const float2* __restrict__ x,    // [B*S] rows of 2 f32
    const f32x4* __restrict__ W,     // [128][2] f32 = 64 f32x4
    const f32x4* __restrict__ pat,   // [S][128] f32: row = 32 f32x4
    const float* __restrict__ vt_in, // [B*S] f32 (written by rank_kernel)
    float* __restrict__ out) {
    const size_t NFE = (size_t)BATCH * SEQ * DIM;
    f32x4* nfe4 = (f32x4*)out;
    f32x4* pfe4 = (f32x4*)(out + NFE);

    const int c = threadIdx.x & 31;  // channel group: d = 4c..4c+3
    f32x4 wa = W[c * 2 + 0];  // W[4c][0], W[4c][1], W[4c+1][0], W[4c+1][1]
    f32x4 wb = W[c * 2 + 1];  // W[4c+2][0..1], W[4c+3][0..1]

    const size_t TOT = (size_t)BATCH * SEQ;
#pragma unroll 2
    for (size_t r = (size_t)blockIdx.x * ROWS_PER_ITER + (threadIdx.x >> 5);
         r < TOT; r += (size_t)EMIT_BLOCKS * ROWS_PER_ITER) {
        int vt = (int)vt_in[r];        // broadcast load within 32-lane group
        int i = (vt >= SEQ) ? 0 : vt;  // vt % SEQ
        if ((unsigned)i >= SEQ) i = 0; // safety clamp

        float2 xv = x[r];
        f32x4 nv;
        nv.x = fmaf(xv.x, wa.x, xv.y * wa.y);
        nv.y = fmaf(xv.x, wa.z, xv.y * wa.w);
        nv.z = fmaf(xv.x, wb.x, xv.y * wb.y);
        nv.w = fmaf(xv.x, wb.z, xv.y * wb.w);
        nfe4[r * 32 + c] = nv;

        pfe4[r * 32 + c] = pat[(size_t)i * 32 + c];  // bit-exact gather
    }
}

extern "C" void kernel_launch(void* const* d_in, const int* in_sizes, int n_in,
                              void* d_out, int out_size, void* d_ws, size_t ws_size,
                              hipStream_t stream) {
    // setup_inputs() dict order: x, W, pattern, solutions (all f32 / int32).
    const void* xp = d_in[0];  // f32 [64,5000,2]
    const void* wp = d_in[1];  // f32 [128,2]
    const void* pp = d_in[2];  // f32 [5000,128]
    const void* sp = d_in[3];  // int32 [64,5000]
    // Defensive remap by element count (W=256, sol=320000; the two 640000s
    // keep relative order: x first, pattern second).
    {
        const void* big[2] = {nullptr, nullptr};
        int nbig = 0;
        const void *w_ = nullptr, *s_ = nullptr;
        for (int i = 0; i < n_in; ++i) {
            if (in_sizes[i] == DIM * 2) w_ = d_in[i];
            else if (in_sizes[i] == BATCH * SEQ) s_ = d_in[i];
            else if (in_sizes[i] == SEQ * DIM && nbig < 2) big[nbig++] = d_in[i];
        }
        if (w_ && s_ && nbig == 2) { wp = w_; sp = s_; xp = big[0]; pp = big[1]; }
    }

    const size_t NFE = (size_t)BATCH * SEQ * DIM;
    float* vt_out = (float*)d_out + 2 * NFE;  // vt region is also an output

    rank_kernel<<<BATCH, TPB1, 0, stream>>>((const int*)sp, vt_out);
    emit_kernel<<<EMIT_BLOCKS, TPB2, 0, stream>>>(
        (const float2*)xp, (const f32x4*)wp, (const f32x4*)pp,
        (const float*)vt_out, (float*)d_out);
}

// Round 4
// 334.207 us; speedup vs baseline: 1.0819x; 1.0819x over previous
//
#include <hip/hip_runtime.h>

#define SEQ 5000
#define BATCH 64
#define DIM 128

#define TPB1 1024            // kernel 1: rank blocks + NFE-stream blocks
#define RANK_BLOCKS BATCH    // first 64 blocks of K1 do list ranking
#define NFE_BLOCKS 960       // remaining blocks stream NFE = x@W^T
#define TPB2 512             // kernel 2: PFE emit
#define PFE_BLOCKS 2048

typedef float f32x4 __attribute__((ext_vector_type(4)));

// ---------------------------------------------------------------------------
// Kernel 1, heterogeneous grid:
//   blocks [0,64):    Wyllie pointer-doubling list ranking of batch b's
//                     successor cycle in LDS (word = (dist<<16)|next, cycle
//                     broken at node 0). After 13 doublings dist[i] = steps
//                     i->0, vt = SEQ - dist, written as f32 to its final
//                     output slot. ~15-20 us on 64 CUs.
//   blocks [64,1024): pure NFE stream (164 MB of writes, no dependence on
//                     ranking) — runs on the other CUs CONCURRENTLY, hiding
//                     the rank latency that was previously serial.
// Kernel boundary makes vt visible to kernel 2 (no intra-grid dependency).
// ---------------------------------------------------------------------------
__global__ __launch_bounds__(TPB1) void rank_nfe_kernel(
    const float2* __restrict__ x,   // [B*S] rows of 2 f32
    const f32x4* __restrict__ W,    // [128][2] f32 = 64 f32x4
    const int* __restrict__ sol,    // [B][S] int32
    float* __restrict__ out) {
    __shared__ unsigned buf[2][SEQ];  // 40 KB (reserved in all blocks; NFE
                                      // blocks still reach 2 blocks/CU = max
                                      // threads, so no occupancy loss)
    const size_t NFE = (size_t)BATCH * SEQ * DIM;

    if (blockIdx.x < RANK_BLOCKS) {
        const int b = blockIdx.x;
        const int* sp = sol + b * SEQ;
        float* vt_out = out + 2 * NFE;

        for (int i = threadIdx.x; i < SEQ; i += TPB1) {
            unsigned nx = (unsigned)sp[i];
            if (nx >= SEQ) nx = 0;  // safety: never triggers on valid input
            buf[0][i] = (i == 0) ? 0u : ((1u << 16) | nx);
        }
        __syncthreads();
        int cur = 0;
#pragma unroll 1
        for (int it = 0; it < 13; ++it) {
            for (int i = threadIdx.x; i < SEQ; i += TPB1) {
                unsigned w  = buf[cur][i];
                unsigned w2 = buf[cur][w & 0xFFFFu];
                buf[cur ^ 1][i] = (w & 0xFFFF0000u) + w2;  // low16 can't carry
            }
            __syncthreads();
            cur ^= 1;
        }
        for (int i = threadIdx.x; i < SEQ; i += TPB1) {
            int vt = SEQ - (int)(buf[cur][i] >> 16);  // 1..5000; node0 -> 5000
            vt_out[(size_t)b * SEQ + i] = (float)vt;
        }
    } else {
        // NFE stream: 32 lanes per row, lane c owns channels 4c..4c+3.
        f32x4* nfe4 = (f32x4*)out;
        const int c = threadIdx.x & 31;
        f32x4 wa = W[c * 2 + 0];  // W[4c][0..1], W[4c+1][0..1]
        f32x4 wb = W[c * 2 + 1];  // W[4c+2][0..1], W[4c+3][0..1]

        const size_t TOT = (size_t)BATCH * SEQ;
        const int ROWS = TPB1 / 32;  // 32 rows per block-iteration
        for (size_t r = (size_t)(blockIdx.x - RANK_BLOCKS) * ROWS +
                        (threadIdx.x >> 5);
             r < TOT; r += (size_t)NFE_BLOCKS * ROWS) {
            float2 xv = x[r];  // 8 B broadcast within half-wave
            f32x4 nv;
            nv.x = fmaf(xv.x, wa.x, xv.y * wa.y);
            nv.y = fmaf(xv.x, wa.z, xv.y * wa.w);
            nv.z = fmaf(xv.x, wb.x, xv.y * wb.y);
            nv.w = fmaf(xv.x, wb.z, xv.y * wb.w);
            __builtin_nontemporal_store(nv, &nfe4[r * 32 + c]);
        }
    }
}

// ---------------------------------------------------------------------------
// Kernel 2: PFE emit. idx = (vt==SEQ) ? 0 : vt, bit-exact 16B gather of
// pattern[idx] (2.56 MB, L2-resident). vt itself was already written by the
// rank blocks. NT stores = round-2 measured-best config.
// ---------------------------------------------------------------------------
__global__ __launch_bounds__(TPB2) void pfe_kernel(
    const f32x4* __restrict__ pat,   // [S][128] f32: row = 32 f32x4
    const float* __restrict__ vt_in, // [B*S] f32 (written by rank blocks)
    float* __restrict__ out) {
    const size_t NFE = (size_t)BATCH * SEQ * DIM;
    f32x4* pfe4 = (f32x4*)(out + NFE);
    const int c = threadIdx.x & 31;

    const size_t TOT = (size_t)BATCH * SEQ;
    const int ROWS = TPB2 / 32;  // 16 rows per block-iteration
    for (size_t r = (size_t)blockIdx.x * ROWS + (threadIdx.x >> 5);
         r < TOT; r += (size_t)PFE_BLOCKS * ROWS) {
        int vt = (int)vt_in[r];        // broadcast load within half-wave
        int i = (vt >= SEQ) ? 0 : vt;  // vt % SEQ
        if ((unsigned)i >= SEQ) i = 0; // safety clamp
        f32x4 pv = pat[(size_t)i * 32 + c];  // bit-exact gather, L2-resident
        __builtin_nontemporal_store(pv, &pfe4[r * 32 + c]);
    }
}

extern "C" void kernel_launch(void* const* d_in, const int* in_sizes, int n_in,
                              void* d_out, int out_size, void* d_ws, size_t ws_size,
                              hipStream_t stream) {
    // setup_inputs() dict order: x, W, pattern, solutions (all f32 / int32).
    const void* xp = d_in[0];  // f32 [64,5000,2]
    const void* wp = d_in[1];  // f32 [128,2]
    const void* pp = d_in[2];  // f32 [5000,128]
    const void* sp = d_in[3];  // int32 [64,5000]
    // Defensive remap by element count (W=256, sol=320000; the two 640000s
    // keep relative order: x first, pattern second).
    {
        const void* big[2] = {nullptr, nullptr};
        int nbig = 0;
        const void *w_ = nullptr, *s_ = nullptr;
        for (int i = 0; i < n_in; ++i) {
            if (in_sizes[i] == DIM * 2) w_ = d_in[i];
            else if (in_sizes[i] == BATCH * SEQ) s_ = d_in[i];
            else if (in_sizes[i] == SEQ * DIM && nbig < 2) big[nbig++] = d_in[i];
        }
        if (w_ && s_ && nbig == 2) { wp = w_; sp = s_; xp = big[0]; pp = big[1]; }
    }

    const size_t NFE = (size_t)BATCH * SEQ * DIM;
    float* vt_region = (float*)d_out + 2 * NFE;

    rank_nfe_kernel<<<RANK_BLOCKS + NFE_BLOCKS, TPB1, 0, stream>>>(
        (const float2*)xp, (const f32x4*)wp, (const int*)sp, (float*)d_out);
    pfe_kernel<<<PFE_BLOCKS, TPB2, 0, stream>>>(
        (const f32x4*)pp, (const float*)vt_region, (float*)d_out);
}